// Round 1
// baseline (4921.717 us; speedup 1.0000x reference)
//
#include <hip/hip_runtime.h>

#define N_PTS 16384
#define KNN   20

typedef unsigned int u32;
typedef const __attribute__((address_space(1))) u32 glob_u32;
typedef __attribute__((address_space(3))) u32 lds_u32;

__device__ __forceinline__ void g2lds16(const float* g, float* l) {
  // async global->LDS, 16B per lane; LDS dest = wave-uniform base + lane*16
  __builtin_amdgcn_global_load_lds((glob_u32*)g, (lds_u32*)l, 16, 0, 0);
}

// Stage 64 rows x F floats from X[row0..row0+64) into LDS `dst` with chunk-XOR
// swizzle: LDS chunk position p holds global chunk (p ^ (row & (F/4-1))).
template<int F>
__device__ __forceinline__ void stage_tile(const float* __restrict__ X, int row0, float* dst) {
  constexpr int CH = F / 4;
  constexpr int CM = CH - 1;
  const int tid = threadIdx.x;
  const int wv = tid >> 6, ln = tid & 63;
  constexpr int NG = 64 * CH;
#pragma unroll
  for (int base = 0; base < NG; base += 256) {
    int g = base + wv * 64 + ln;
    int r = g / CH;
    int p = g & CM;
    int sc = p ^ (r & CM);  // pre-swizzled global source chunk
    const float* src = X + (size_t)(row0 + r) * F + sc * 4;
    g2lds16(src, dst + (size_t)(base + wv * 64) * 4);
  }
}

// Fused distance + top-20 kNN. Score s = |c|^2 - 2 q.c  (same order as d2).
// Block: 256 thr = 4 waves; 64 queries/block (16 per wave); candidate tiles of 64,
// double-buffered. Per-lane micro-tile 4q x 4c.
template<int F>
__global__ __launch_bounds__(256) void knn_kernel(const float* __restrict__ X,
                                                  const float* __restrict__ sqn,
                                                  int* __restrict__ out_idx) {
  constexpr int CH = F / 4, CM = CH - 1;
  constexpr int NT = N_PTS / 64;
  extern __shared__ float lds[];
  float* qt  = lds;                       // 64*F
  float* ct0 = qt + 64 * F;               // 2 * 64*F (double buffer)
  float* S   = ct0 + 2 * 64 * F;          // 64*68 (pitch 68 -> 2-way banks)
  float* Ld  = S + 64 * 68;               // 64*20 sorted distances
  int*   Li  = (int*)(Ld + 64 * KNN);     // 64*20 indices
  float* thr = (float*)(Li + 64 * KNN);   // 64 thresholds (current 20th value)

  const int tid = threadIdx.x;
  const int wv = tid >> 6, ln = tid & 63;
  const int qg = ln >> 4, cg = ln & 15;
  const int q0 = blockIdx.x * 64;

  // init per-query lists (wave-local rows)
#pragma unroll
  for (int k = 0; k < 16; ++k) {
    int q = wv * 16 + k;
    if (ln < KNN) { Ld[q * KNN + ln] = 3.0e38f; Li[q * KNN + ln] = 0; }
  }
  if (ln < 16) thr[wv * 16 + ln] = 3.0e38f;

  stage_tile<F>(X, q0, qt);
  stage_tile<F>(X, 0, ct0);
  __syncthreads();

  int qr[4];
#pragma unroll
  for (int i = 0; i < 4; i++) qr[i] = wv * 16 + qg * 4 + i;

  for (int t = 0; t < NT; ++t) {
    if (t + 1 < NT) stage_tile<F>(X, (t + 1) * 64, ct0 + ((t + 1) & 1) * 64 * F);

    const float4* qt4 = (const float4*)qt;
    const float4* ct4 = (const float4*)(ct0 + (t & 1) * 64 * F);
    float acc[4][4];
#pragma unroll
    for (int i = 0; i < 4; i++)
#pragma unroll
      for (int j = 0; j < 4; j++) acc[i][j] = 0.f;

#pragma unroll 4
    for (int d4 = 0; d4 < CH; ++d4) {
      float4 qv[4], cv[4];
#pragma unroll
      for (int i = 0; i < 4; i++) qv[i] = qt4[qr[i] * CH + (d4 ^ (qr[i] & CM))];
#pragma unroll
      for (int j = 0; j < 4; j++) { int c = cg + 16 * j; cv[j] = ct4[c * CH + (d4 ^ (c & CM))]; }
#pragma unroll
      for (int i = 0; i < 4; i++)
#pragma unroll
        for (int j = 0; j < 4; j++)
          acc[i][j] += qv[i].x * cv[j].x + qv[i].y * cv[j].y + qv[i].z * cv[j].z + qv[i].w * cv[j].w;
    }

    const int c0 = t * 64;
    float cn[4];
#pragma unroll
    for (int j = 0; j < 4; j++) cn[j] = sqn[c0 + cg + 16 * j];
#pragma unroll
    for (int i = 0; i < 4; i++)
#pragma unroll
      for (int j = 0; j < 4; j++)
        S[qr[i] * 68 + cg + 16 * j] = cn[j] - 2.f * acc[i][j];
    // S rows are wave-exclusive: no barrier needed before this wave reads them.

#pragma unroll 1
    for (int k = 0; k < 16; ++k) {
      int q = wv * 16 + k;
      float s = S[q * 68 + ln];
      float th = thr[q];
      unsigned long long m = __ballot(s < th);
      while (m) {
        int L = __ffsll(m) - 1;
        m &= m - 1;
        float sv = __shfl(s, L);
        if (sv >= th) continue;  // threshold may have tightened
        int ci = c0 + L;
        float dcur = (ln < KNN) ? Ld[q * KNN + ln] : 3.0e38f;
        int   icur = (ln < KNN) ? Li[q * KNN + ln] : 0;
        unsigned long long le = __ballot(dcur <= sv);
        int p = __popcll(le & 0xFFFFFull);   // insertion position (<=19)
        float dprev = __shfl_up(dcur, 1);
        int   iprev = __shfl_up(icur, 1);
        float nd = (ln < p) ? dcur : ((ln == p) ? sv : dprev);
        int   ni = (ln < p) ? icur : ((ln == p) ? ci : iprev);
        if (ln < KNN) { Ld[q * KNN + ln] = nd; Li[q * KNN + ln] = ni; }
        th = __shfl(nd, 19);
      }
      if (ln == 0) thr[q] = th;
    }
    __syncthreads();  // drains stage of next tile; protects ct buffers
  }

#pragma unroll 1
  for (int k = 0; k < 16; ++k) {
    int q = wv * 16 + k;
    if (ln < KNN) out_idx[(size_t)(q0 + q) * KNN + ln] = Li[q * KNN + ln];
  }
}

// x1 = relu(pos @ W1 + b1), plus squared row norms. One wave per point.
__global__ __launch_bounds__(256) void mlp1_kernel(const float* __restrict__ pos,
                                                   const float* __restrict__ W1,
                                                   const float* __restrict__ b1,
                                                   float* __restrict__ x1,
                                                   float* __restrict__ sqn) {
  int i = blockIdx.x * 4 + (threadIdx.x >> 6);
  int o = threadIdx.x & 63;
  float p0 = pos[i * 3], p1 = pos[i * 3 + 1], p2 = pos[i * 3 + 2];
  float v = p0 * W1[o] + p1 * W1[64 + o] + p2 * W1[128 + o] + b1[o];
  v = fmaxf(v, 0.f);
  x1[(size_t)i * 64 + o] = v;
  float ss = v * v;
#pragma unroll
  for (int d = 32; d; d >>= 1) ss += __shfl_xor(ss, d);
  if (o == 0) sqn[i] = ss;
}

template<int F>
__global__ __launch_bounds__(256) void norm_kernel(const float* __restrict__ x,
                                                   float* __restrict__ sqn) {
  int i = blockIdx.x * 4 + (threadIdx.x >> 6);
  int l = threadIdx.x & 63;
  float ss = 0.f;
#pragma unroll
  for (int d = l; d < F; d += 64) { float v = x[(size_t)i * F + d]; ss += v * v; }
#pragma unroll
  for (int d = 32; d; d >>= 1) ss += __shfl_xor(ss, d);
  if (l == 0) sqn[i] = ss;
}

// C[N x OUT] = X[N x K] @ W[K x OUT] (+ bias). Register-tiled 4 rows x float4.
template<int K, int OUT, bool BIAS>
__global__ __launch_bounds__(256) void lin_kernel(const float* __restrict__ X,
                                                  const float* __restrict__ W,
                                                  const float* __restrict__ bias,
                                                  float* __restrict__ C) {
  constexpr int XD = OUT / 4;
  constexpr int YD = 256 / XD;
  constexpr int R = YD * 4;
  __shared__ float xs[R * K];
  const int tid = threadIdx.x;
  const int tx = tid % XD, ty = tid / XD;
  const size_t r0 = (size_t)blockIdx.x * R;
  const float4* Xv = (const float4*)(X + r0 * K);
  float4* xsv = (float4*)xs;
#pragma unroll
  for (int i2 = tid; i2 < R * K / 4; i2 += 256) xsv[i2] = Xv[i2];
  __syncthreads();
  float4 acc[4];
#pragma unroll
  for (int i = 0; i < 4; i++) acc[i] = make_float4(0.f, 0.f, 0.f, 0.f);
  const float4* W4 = (const float4*)W;
#pragma unroll 8
  for (int k = 0; k < K; ++k) {
    float4 wv = W4[k * XD + tx];
#pragma unroll
    for (int i = 0; i < 4; i++) {
      float xv = xs[(ty * 4 + i) * K + k];
      acc[i].x += xv * wv.x; acc[i].y += xv * wv.y;
      acc[i].z += xv * wv.z; acc[i].w += xv * wv.w;
    }
  }
  float4 bv = make_float4(0.f, 0.f, 0.f, 0.f);
  if (BIAS) bv = ((const float4*)bias)[tx];
#pragma unroll
  for (int i = 0; i < 4; i++) {
    float4 o;
    o.x = acc[i].x + bv.x; o.y = acc[i].y + bv.y;
    o.z = acc[i].z + bv.z; o.w = acc[i].w + bv.w;
    ((float4*)(C + (r0 + ty * 4 + i) * OUT))[tx] = o;
  }
}

// out_i = relu(P_i + max_j Q[idx[i][j]])
template<int OUT>
__global__ void maxpool_kernel(const float* __restrict__ P, const float* __restrict__ Q,
                               const int* __restrict__ idx, float* __restrict__ xo) {
  __shared__ int nb[KNN];
  int i = blockIdx.x;
  if (threadIdx.x < KNN) nb[threadIdx.x] = idx[(size_t)i * KNN + threadIdx.x];
  __syncthreads();
  int o = threadIdx.x;
  float m = -3.0e38f;
#pragma unroll
  for (int j = 0; j < KNN; j++) m = fmaxf(m, Q[(size_t)nb[j] * OUT + o]);
  float p = P[(size_t)i * OUT + o];
  xo[(size_t)i * OUT + o] = fmaxf(p + m, 0.f);
}

// Wp[k][o] = We[k][o] - We[K+k][o]
__global__ void wsub_kernel(const float* __restrict__ We, float* __restrict__ Wp, int total) {
  int t = blockIdx.x * 256 + threadIdx.x;
  if (t < total) Wp[t] = We[t] - We[total + t];
}

extern "C" void kernel_launch(void* const* d_in, const int* in_sizes, int n_in,
                              void* d_out, int out_size, void* d_ws, size_t ws_size,
                              hipStream_t stream) {
  const float* pos = (const float*)d_in[0];
  const float* W1  = (const float*)d_in[1];
  const float* b1  = (const float*)d_in[2];
  const float* We1 = (const float*)d_in[3];
  const float* be1 = (const float*)d_in[4];
  const float* We2 = (const float*)d_in[5];
  const float* be2 = (const float*)d_in[6];
  const float* W2  = (const float*)d_in[7];
  const float* b2  = (const float*)d_in[8];
  float* out = (float*)d_out;

  const size_t N = N_PTS;
  float* ws  = (float*)d_ws;
  float* x1  = ws;               // N*64
  float* P1  = x1 + N * 64;      // N*128
  float* Q1  = P1 + N * 128;     // N*128
  float* x2  = Q1 + N * 128;     // N*128
  float* P2  = x2 + N * 128;     // N*256
  float* Q2  = P2 + N * 256;     // N*256
  float* x3  = Q2 + N * 256;     // N*256
  float* sqn = x3 + N * 256;     // N (reused for x1 then x2 norms)
  float* Wp1 = sqn + N;          // 64*128
  float* Wp2 = Wp1 + 64 * 128;   // 128*256
  int* idx1  = (int*)(Wp2 + 128 * 256);  // N*20
  int* idx2  = idx1 + N * KNN;           // N*20
  size_t need = (size_t)((char*)(idx2 + N * KNN) - (char*)d_ws);
  if (ws_size < need) return;  // insufficient scratch -> leave output poisoned (visible failure)

  size_t lds64  = (size_t)(64 * 64 * 3 + 64 * 68 + 64 * KNN * 2 + 64) * 4;
  size_t lds128 = (size_t)(64 * 128 * 3 + 64 * 68 + 64 * KNN * 2 + 64) * 4;
  hipFuncSetAttribute(reinterpret_cast<const void*>(&knn_kernel<64>),
                      hipFuncAttributeMaxDynamicSharedMemorySize, (int)lds64);
  hipFuncSetAttribute(reinterpret_cast<const void*>(&knn_kernel<128>),
                      hipFuncAttributeMaxDynamicSharedMemorySize, (int)lds128);

  wsub_kernel<<<(64 * 128 + 255) / 256, 256, 0, stream>>>(We1, Wp1, 64 * 128);
  wsub_kernel<<<(128 * 256 + 255) / 256, 256, 0, stream>>>(We2, Wp2, 128 * 256);

  mlp1_kernel<<<N / 4, 256, 0, stream>>>(pos, W1, b1, x1, sqn);
  knn_kernel<64><<<N / 64, 256, lds64, stream>>>(x1, sqn, idx1);
  lin_kernel<64, 128, true ><<<N / 32, 256, 0, stream>>>(x1, Wp1, be1, P1);
  lin_kernel<64, 128, false><<<N / 32, 256, 0, stream>>>(x1, We1 + 64 * 128, nullptr, Q1);
  maxpool_kernel<128><<<N, 128, 0, stream>>>(P1, Q1, idx1, x2);

  norm_kernel<128><<<N / 4, 256, 0, stream>>>(x2, sqn);
  knn_kernel<128><<<N / 64, 256, lds128, stream>>>(x2, sqn, idx2);
  lin_kernel<128, 256, true ><<<N / 16, 256, 0, stream>>>(x2, Wp2, be2, P2);
  lin_kernel<128, 256, false><<<N / 16, 256, 0, stream>>>(x2, We2 + 128 * 256, nullptr, Q2);
  maxpool_kernel<256><<<N, 256, 0, stream>>>(P2, Q2, idx2, x3);

  lin_kernel<256, 128, true ><<<N / 32, 256, 0, stream>>>(x3, W2, b2, out);
}

// Round 3
// 3280.573 us; speedup vs baseline: 1.5003x; 1.5003x over previous
//
#include <hip/hip_runtime.h>
#include <hip/hip_bf16.h>

#define N_PTS 16384
#define KNN   20
#define LIST  32   // approx-stage list width (containment margin for exact refine)

typedef unsigned int u32;
typedef const __attribute__((address_space(1))) u32 glob_u32;
typedef __attribute__((address_space(3))) u32 lds_u32;

typedef __attribute__((ext_vector_type(8))) short bf16x8;
typedef __attribute__((ext_vector_type(4))) float f32x4;

__device__ __forceinline__ void g2lds16(const void* g, void* l) {
  // async global->LDS, 16B per lane; LDS dest = wave-uniform base + lane*16
  __builtin_amdgcn_global_load_lds((glob_u32*)g, (lds_u32*)l, 16, 0, 0);
}

// Stage 64 rows x F bf16 from X[row0..) into LDS with chunk-XOR swizzle:
// LDS 16B-chunk position p of row r holds global chunk (p ^ (r & (NCH-1))).
template<int F>
__device__ __forceinline__ void stage_c(const ushort* __restrict__ X, int row0, ushort* dst) {
  constexpr int NCH = F / 8;            // 16B chunks per row (128->16, 64->8)
  constexpr int TOT = 64 * NCH;
  const int tid = threadIdx.x;
  const int wv = tid >> 6, ln = tid & 63;
#pragma unroll
  for (int base = 0; base < TOT; base += 256) {
    int g = base + wv * 64 + ln;
    int r = g / NCH;
    int p = g % NCH;
    int sc = p ^ (r & (NCH - 1));       // pre-swizzled global source chunk
    g2lds16(X + (size_t)(row0 + r) * F + sc * 8,
            dst + (size_t)(base + wv * 64) * 8);   // wave-uniform LDS base
  }
}

// Load one 16x32 bf16 MFMA fragment from a swizzled 64-row LDS tile.
// lane: row = rbase + (ln&15), k-chunk pc = kc*4 + (ln>>4), de-swizzled.
template<int F>
__device__ __forceinline__ bf16x8 ldfrag(const ushort* buf, int rbase, int kc, int ln) {
  constexpr int NCH = F / 8;
  int r  = rbase + (ln & 15);
  int pc = kc * 4 + (ln >> 4);
  int sp = pc ^ (r & (NCH - 1));
  return *(const bf16x8*)(buf + (size_t)r * F + sp * 8);
}

// Fused bf16x3-MFMA distance + top-32 approx kNN. Score s = |c|^2 - 2 q.c.
// Block: 256 thr = 4 waves; wave owns 16 queries; candidate tiles of 64, dbuf.
template<int F>
__global__ __launch_bounds__(256) void knn_kernel(const ushort* __restrict__ Xh,
                                                  const ushort* __restrict__ Xl,
                                                  const float* __restrict__ sqn,
                                                  int* __restrict__ out_cand) {
  constexpr int KC = F / 32;            // 32-k chunks per row
  constexpr int NT = N_PTS / 64;
  extern __shared__ ushort lds_raw[];
  ushort* cb = lds_raw;                           // [2 buf][2 part][64*F]
  float*  S   = (float*)(cb + 4 * 64 * F);        // 64*68 (pitch 68)
  float*  Ld  = S + 64 * 68;                      // 64*32 sorted distances
  ushort* Li  = (ushort*)(Ld + 64 * LIST);        // 64*32 indices (ushort!)
  float*  thr = (float*)(Li + 64 * LIST);         // 64 thresholds

  const int tid = threadIdx.x;
  const int wv = tid >> 6, ln = tid & 63;
  const int q0 = blockIdx.x * 64;
  const int g4 = (ln >> 4) * 4;

  // init per-query lists (wave-local rows)
#pragma unroll
  for (int k = 0; k < 16; ++k) {
    int q = wv * 16 + k;
    if (ln < LIST) { Ld[q * LIST + ln] = 3.0e38f; Li[q * LIST + ln] = 0; }
  }
  if (ln < 16) thr[wv * 16 + ln] = 3.0e38f;

  // stage query tile into buf1, load A fragments (hi/lo) into registers
  ushort* buf0 = cb;
  ushort* buf1 = cb + 2 * 64 * F;
  stage_c<F>(Xh, q0, buf1);
  stage_c<F>(Xl, q0, buf1 + 64 * F);
  __syncthreads();
  bf16x8 ah[KC], al[KC];
#pragma unroll
  for (int kc = 0; kc < KC; ++kc) {
    ah[kc] = ldfrag<F>(buf1, wv * 16, kc, ln);
    al[kc] = ldfrag<F>(buf1 + 64 * F, wv * 16, kc, ln);
  }
  // stage candidate tile 0 into buf0 (A-frag ds_reads drain at the barrier)
  stage_c<F>(Xh, 0, buf0);
  stage_c<F>(Xl, 0, buf0 + 64 * F);
  __syncthreads();

  for (int t = 0; t < NT; ++t) {
    const int c0 = t * 64;
    float cn[4];
#pragma unroll
    for (int cg = 0; cg < 4; ++cg) cn[cg] = sqn[c0 + cg * 16 + (ln & 15)];

    // prefetch next tile into the other buffer
    if (t + 1 < NT) {
      ushort* nb = cb + (size_t)((t + 1) & 1) * (2 * 64 * F);
      stage_c<F>(Xh, (t + 1) * 64, nb);
      stage_c<F>(Xl, (t + 1) * 64, nb + 64 * F);
    }

    const ushort* hi = cb + (size_t)(t & 1) * (2 * 64 * F);
    const ushort* lo = hi + 64 * F;

    // MFMA: 4 candidate groups x KC k-chunks x 3 (bf16x3)
#pragma unroll
    for (int cg = 0; cg < 4; ++cg) {
      f32x4 a = {0.f, 0.f, 0.f, 0.f};
#pragma unroll
      for (int kc = 0; kc < KC; ++kc) {
        bf16x8 bh = ldfrag<F>(hi, cg * 16, kc, ln);
        bf16x8 bl = ldfrag<F>(lo, cg * 16, kc, ln);
        a = __builtin_amdgcn_mfma_f32_16x16x32_bf16(ah[kc], bh, a, 0, 0, 0);
        a = __builtin_amdgcn_mfma_f32_16x16x32_bf16(al[kc], bh, a, 0, 0, 0);
        a = __builtin_amdgcn_mfma_f32_16x16x32_bf16(ah[kc], bl, a, 0, 0, 0);
      }
      float cnv = cn[cg];
#pragma unroll
      for (int r = 0; r < 4; ++r)
        S[(wv * 16 + g4 + r) * 68 + cg * 16 + (ln & 15)] = cnv - 2.0f * a[r];
    }
    // S rows are wave-exclusive: no barrier needed before this wave reads them.

#pragma unroll 1
    for (int k = 0; k < 16; ++k) {
      int q = wv * 16 + k;
      float s = S[q * 68 + ln];
      float th = thr[q];
      unsigned long long m = __ballot(s < th);
      while (m) {
        int L = __ffsll(m) - 1;
        m &= m - 1;
        float sv = __shfl(s, L);
        if (sv >= th) continue;  // threshold may have tightened
        int ci = c0 + L;
        float dcur = (ln < LIST) ? Ld[q * LIST + ln] : 3.0e38f;
        int   icur = (ln < LIST) ? (int)Li[q * LIST + ln] : 0;
        unsigned long long le = __ballot(dcur <= sv);
        int p = __popcll(le & 0xFFFFFFFFull);   // insertion position (<=31)
        float dprev = __shfl_up(dcur, 1);
        int   iprev = __shfl_up(icur, 1);
        float nd = (ln < p) ? dcur : ((ln == p) ? sv : dprev);
        int   ni = (ln < p) ? icur : ((ln == p) ? ci : iprev);
        if (ln < LIST) { Ld[q * LIST + ln] = nd; Li[q * LIST + ln] = (ushort)ni; }
        th = __shfl(nd, LIST - 1);
      }
      if (ln == 0) thr[q] = th;
    }
    __syncthreads();  // drains next-tile stage; protects c-buffers
  }

#pragma unroll 1
  for (int k = 0; k < 16; ++k) {
    int q = wv * 16 + k;
    if (ln < LIST) out_cand[(size_t)(q0 + q) * LIST + ln] = (int)Li[q * LIST + ln];
  }
}

// Exact fp32 re-rank of the 32 approx candidates -> true fp32 top-20 set.
// One wave per query; lane l: candidate (l&31), feature half (l>>5).
template<int F>
__global__ __launch_bounds__(256) void refine_kernel(const float* __restrict__ X,
                                                     const float* __restrict__ sqn,
                                                     const int* __restrict__ cand,
                                                     int* __restrict__ out_idx) {
  const int wv = threadIdx.x >> 6, ln = threadIdx.x & 63;
  const int q = blockIdx.x * 4 + wv;
  const int half = ln >> 5;
  int ci = cand[(size_t)q * LIST + (ln & 31)];
  const float* qrow = X + (size_t)q * F + half * (F / 2);
  const float* crow = X + (size_t)ci * F + half * (F / 2);
  float partial = 0.f;
#pragma unroll
  for (int d = 0; d < F / 2; d += 4) {
    float4 qv = *(const float4*)(qrow + d);
    float4 cv = *(const float4*)(crow + d);
    partial += qv.x * cv.x + qv.y * cv.y + qv.z * cv.z + qv.w * cv.w;
  }
  partial += __shfl_xor(partial, 32);
  float s = sqn[ci] - 2.0f * partial;
  // rank by (score asc, index asc) among the 32 candidates
  int rank = 0;
#pragma unroll 1
  for (int j = 0; j < LIST; ++j) {
    float sj = __shfl(s, j);
    int   cj = __shfl(ci, j);
    rank += (sj < s) || (sj == s && cj < ci);
  }
  bool win = (ln < LIST) && (rank < KNN);
  unsigned long long wm = __ballot(win);
  int pos = __popcll(wm & ((1ull << ln) - 1));
  if (win) out_idx[(size_t)q * KNN + pos] = ci;
}

// x1 = relu(pos @ W1 + b1) + bf16 hi/lo split + squared row norms.
__global__ __launch_bounds__(256) void mlp1_kernel(const float* __restrict__ pos,
                                                   const float* __restrict__ W1,
                                                   const float* __restrict__ b1,
                                                   float* __restrict__ x1,
                                                   ushort* __restrict__ xh,
                                                   ushort* __restrict__ xl,
                                                   float* __restrict__ sqn) {
  int i = blockIdx.x * 4 + (threadIdx.x >> 6);
  int o = threadIdx.x & 63;
  float p0 = pos[i * 3], p1 = pos[i * 3 + 1], p2 = pos[i * 3 + 2];
  float v = p0 * W1[o] + p1 * W1[64 + o] + p2 * W1[128 + o] + b1[o];
  v = fmaxf(v, 0.f);
  x1[(size_t)i * 64 + o] = v;
  __hip_bfloat16 h = __float2bfloat16(v);
  float hv = __bfloat162float(h);
  __hip_bfloat16 l2 = __float2bfloat16(v - hv);
  xh[(size_t)i * 64 + o] = *(ushort*)&h;
  xl[(size_t)i * 64 + o] = *(ushort*)&l2;
  float ss = v * v;
#pragma unroll
  for (int d = 32; d; d >>= 1) ss += __shfl_xor(ss, d);
  if (o == 0) sqn[i] = ss;
}

// hi/lo bf16 split + squared norms for an existing fp32 feature array.
template<int F>
__global__ __launch_bounds__(256) void prep_kernel(const float* __restrict__ x,
                                                   ushort* __restrict__ xh,
                                                   ushort* __restrict__ xl,
                                                   float* __restrict__ sqn) {
  int i = blockIdx.x * 4 + (threadIdx.x >> 6);
  int l = threadIdx.x & 63;
  float ss = 0.f;
#pragma unroll
  for (int d = l; d < F; d += 64) {
    float v = x[(size_t)i * F + d];
    ss += v * v;
    __hip_bfloat16 h = __float2bfloat16(v);
    float hv = __bfloat162float(h);
    __hip_bfloat16 l2 = __float2bfloat16(v - hv);
    xh[(size_t)i * F + d] = *(ushort*)&h;
    xl[(size_t)i * F + d] = *(ushort*)&l2;
  }
#pragma unroll
  for (int d = 32; d; d >>= 1) ss += __shfl_xor(ss, d);
  if (l == 0) sqn[i] = ss;
}

// C[N x OUT] = X[N x K] @ W[K x OUT] (+ bias). Register-tiled 4 rows x float4.
template<int K, int OUT, bool BIAS>
__global__ __launch_bounds__(256) void lin_kernel(const float* __restrict__ X,
                                                  const float* __restrict__ W,
                                                  const float* __restrict__ bias,
                                                  float* __restrict__ C) {
  constexpr int XD = OUT / 4;
  constexpr int YD = 256 / XD;
  constexpr int R = YD * 4;
  __shared__ float xs[R * K];
  const int tid = threadIdx.x;
  const int tx = tid % XD, ty = tid / XD;
  const size_t r0 = (size_t)blockIdx.x * R;
  const float4* Xv = (const float4*)(X + r0 * K);
  float4* xsv = (float4*)xs;
#pragma unroll
  for (int i2 = tid; i2 < R * K / 4; i2 += 256) xsv[i2] = Xv[i2];
  __syncthreads();
  float4 acc[4];
#pragma unroll
  for (int i = 0; i < 4; i++) acc[i] = make_float4(0.f, 0.f, 0.f, 0.f);
  const float4* W4 = (const float4*)W;
#pragma unroll 8
  for (int k = 0; k < K; ++k) {
    float4 wv = W4[k * XD + tx];
#pragma unroll
    for (int i = 0; i < 4; i++) {
      float xv = xs[(ty * 4 + i) * K + k];
      acc[i].x += xv * wv.x; acc[i].y += xv * wv.y;
      acc[i].z += xv * wv.z; acc[i].w += xv * wv.w;
    }
  }
  float4 bv = make_float4(0.f, 0.f, 0.f, 0.f);
  if (BIAS) bv = ((const float4*)bias)[tx];
#pragma unroll
  for (int i = 0; i < 4; i++) {
    float4 o;
    o.x = acc[i].x + bv.x; o.y = acc[i].y + bv.y;
    o.z = acc[i].z + bv.z; o.w = acc[i].w + bv.w;
    ((float4*)(C + (r0 + ty * 4 + i) * OUT))[tx] = o;
  }
}

// out_i = relu(P_i + max_j Q[idx[i][j]])
template<int OUT>
__global__ void maxpool_kernel(const float* __restrict__ P, const float* __restrict__ Q,
                               const int* __restrict__ idx, float* __restrict__ xo) {
  __shared__ int nb[KNN];
  int i = blockIdx.x;
  if (threadIdx.x < KNN) nb[threadIdx.x] = idx[(size_t)i * KNN + threadIdx.x];
  __syncthreads();
  int o = threadIdx.x;
  float m = -3.0e38f;
#pragma unroll
  for (int j = 0; j < KNN; j++) m = fmaxf(m, Q[(size_t)nb[j] * OUT + o]);
  float p = P[(size_t)i * OUT + o];
  xo[(size_t)i * OUT + o] = fmaxf(p + m, 0.f);
}

// Wp[k][o] = We[k][o] - We[K+k][o]
__global__ void wsub_kernel(const float* __restrict__ We, float* __restrict__ Wp, int total) {
  int t = blockIdx.x * 256 + threadIdx.x;
  if (t < total) Wp[t] = We[t] - We[total + t];
}

extern "C" void kernel_launch(void* const* d_in, const int* in_sizes, int n_in,
                              void* d_out, int out_size, void* d_ws, size_t ws_size,
                              hipStream_t stream) {
  const float* pos = (const float*)d_in[0];
  const float* W1  = (const float*)d_in[1];
  const float* b1  = (const float*)d_in[2];
  const float* We1 = (const float*)d_in[3];
  const float* be1 = (const float*)d_in[4];
  const float* We2 = (const float*)d_in[5];
  const float* be2 = (const float*)d_in[6];
  const float* W2  = (const float*)d_in[7];
  const float* b2  = (const float*)d_in[8];
  float* out = (float*)d_out;

  const size_t N = N_PTS;
  float* ws  = (float*)d_ws;
  float* x1  = ws;               // N*64
  float* P1  = x1 + N * 64;      // N*128
  float* Q1  = P1 + N * 128;     // N*128
  float* x2  = Q1 + N * 128;     // N*128
  float* P2  = x2 + N * 128;     // N*256
  float* Q2  = P2 + N * 256;     // N*256
  float* x3  = Q2 + N * 256;     // N*256
  float* sqn = x3 + N * 256;     // N (x1 norms, then x2 norms)
  float* Wp1 = sqn + N;          // 64*128
  float* Wp2 = Wp1 + 64 * 128;   // 128*256
  int* idx1  = (int*)(Wp2 + 128 * 256);  // N*20
  int* idx2  = idx1 + N * KNN;           // N*20
  int* cand  = idx2 + N * KNN;           // N*32 (reused by both layers)
  ushort* X1h = (ushort*)(cand + N * LIST); // N*64
  ushort* X1l = X1h + N * 64;               // N*64
  ushort* X2h = X1l + N * 64;               // N*128
  ushort* X2l = X2h + N * 128;              // N*128
  size_t need = (size_t)((char*)(X2l + N * 128) - (char*)d_ws);
  if (ws_size < need) return;  // insufficient scratch -> visible failure

  auto lds_bytes = [](int F) {
    return (size_t)(4 * 64 * F) * 2 + (size_t)(64 * 68) * 4 +
           (size_t)(64 * LIST) * 4 + (size_t)(64 * LIST) * 2 + 64 * 4;
  };
  size_t lds64 = lds_bytes(64), lds128 = lds_bytes(128);
  hipFuncSetAttribute(reinterpret_cast<const void*>(&knn_kernel<64>),
                      hipFuncAttributeMaxDynamicSharedMemorySize, (int)lds64);
  hipFuncSetAttribute(reinterpret_cast<const void*>(&knn_kernel<128>),
                      hipFuncAttributeMaxDynamicSharedMemorySize, (int)lds128);

  wsub_kernel<<<(64 * 128 + 255) / 256, 256, 0, stream>>>(We1, Wp1, 64 * 128);
  wsub_kernel<<<(128 * 256 + 255) / 256, 256, 0, stream>>>(We2, Wp2, 128 * 256);

  mlp1_kernel<<<N / 4, 256, 0, stream>>>(pos, W1, b1, x1, X1h, X1l, sqn);
  knn_kernel<64><<<N / 64, 256, lds64, stream>>>(X1h, X1l, sqn, cand);
  refine_kernel<64><<<N / 4, 256, 0, stream>>>(x1, sqn, cand, idx1);
  lin_kernel<64, 128, true ><<<N / 32, 256, 0, stream>>>(x1, Wp1, be1, P1);
  lin_kernel<64, 128, false><<<N / 32, 256, 0, stream>>>(x1, We1 + 64 * 128, nullptr, Q1);
  maxpool_kernel<128><<<N, 128, 0, stream>>>(P1, Q1, idx1, x2);

  prep_kernel<128><<<N / 4, 256, 0, stream>>>(x2, X2h, X2l, sqn);
  knn_kernel<128><<<N / 64, 256, lds128, stream>>>(X2h, X2l, sqn, cand);
  refine_kernel<128><<<N / 4, 256, 0, stream>>>(x2, sqn, cand, idx2);
  lin_kernel<128, 256, true ><<<N / 16, 256, 0, stream>>>(x2, Wp2, be2, P2);
  lin_kernel<128, 256, false><<<N / 16, 256, 0, stream>>>(x2, We2 + 128 * 256, nullptr, Q2);
  maxpool_kernel<256><<<N, 256, 0, stream>>>(P2, Q2, idx2, x3);

  lin_kernel<256, 128, true ><<<N / 32, 256, 0, stream>>>(x3, W2, b2, out);
}

// Round 4
// 2849.682 us; speedup vs baseline: 1.7271x; 1.1512x over previous
//
#include <hip/hip_runtime.h>
#include <hip/hip_bf16.h>

#define N_PTS 16384
#define KNN   20
#define LIST  32   // approx-stage list width per candidate-half (refine is exact)

typedef unsigned int u32;
typedef const __attribute__((address_space(1))) u32 glob_u32;
typedef __attribute__((address_space(3))) u32 lds_u32;

typedef __attribute__((ext_vector_type(8))) short bf16x8;
typedef __attribute__((ext_vector_type(4))) float f32x4;

__device__ __forceinline__ void g2lds16(const void* g, void* l) {
  // async global->LDS, 16B per lane; LDS dest = wave-uniform base + lane*16
  __builtin_amdgcn_global_load_lds((glob_u32*)g, (lds_u32*)l, 16, 0, 0);
}

// Stage 64 rows x F bf16 from X[row0..) into LDS with chunk-XOR swizzle:
// LDS 16B-chunk position p of row r holds global chunk (p ^ (r & (NCH-1))).
template<int F>
__device__ __forceinline__ void stage_c(const ushort* __restrict__ X, int row0, ushort* dst) {
  constexpr int NCH = F / 8;            // 16B chunks per row (128->16, 64->8)
  constexpr int TOT = 64 * NCH;
  const int tid = threadIdx.x;
  const int wv = tid >> 6, ln = tid & 63;
#pragma unroll
  for (int base = 0; base < TOT; base += 256) {
    int g = base + wv * 64 + ln;
    int r = g / NCH;
    int p = g % NCH;
    int sc = p ^ (r & (NCH - 1));       // pre-swizzled global source chunk
    g2lds16(X + (size_t)(row0 + r) * F + sc * 8,
            dst + (size_t)(base + wv * 64) * 8);   // wave-uniform LDS base
  }
}

// Load one 16x32 bf16 MFMA fragment from a swizzled 64-row LDS tile.
// lane: row = rbase + (ln&15), k-chunk pc = kc*4 + (ln>>4), de-swizzled.
template<int F>
__device__ __forceinline__ bf16x8 ldfrag(const ushort* buf, int rbase, int kc, int ln) {
  constexpr int NCH = F / 8;
  int r  = rbase + (ln & 15);
  int pc = kc * 4 + (ln >> 4);
  int sp = pc ^ (r & (NCH - 1));
  return *(const bf16x8*)(buf + (size_t)r * F + sp * 8);
}

// Fused bf16x3-MFMA distance + top-32 approx kNN over HALF the candidate range.
// Block: 256 thr = 4 waves; wave owns 16 queries; 64-cand tiles, double-buffered.
// Selection: register ballots straight from MFMA accumulators (no LDS S-tile).
template<int F>
__global__ __launch_bounds__(256) void knn_kernel(const ushort* __restrict__ Xh,
                                                  const ushort* __restrict__ Xl,
                                                  const float* __restrict__ sqn,
                                                  int* __restrict__ out_cand) {
  constexpr int KC = F / 32;            // 32-k chunks per row
  constexpr int NC = N_PTS / 2;         // candidates per block (2-way split)
  constexpr int NT = NC / 64;
  extern __shared__ ushort lds_raw[];
  ushort* cb  = lds_raw;                          // [2 buf][2 part][64*F]
  float*  Ld  = (float*)(cb + 4 * 64 * F);        // 64*32 sorted distances
  ushort* Li  = (ushort*)(Ld + 64 * LIST);        // 64*32 indices

  const int tid = threadIdx.x;
  const int wv = tid >> 6, ln = tid & 63;
  const int q0 = (blockIdx.x >> 1) * 64;
  const int hf = blockIdx.x & 1;
  const int cbase = hf * NC;

  // init per-query lists (wave-local rows)
#pragma unroll
  for (int k = 0; k < 16; ++k) {
    int q = wv * 16 + k;
    if (ln < LIST) { Ld[q * LIST + ln] = 3.0e38f; Li[q * LIST + ln] = 0; }
  }
  // thresholds: thr_reg lane l<16 holds 32nd-best for query wv*16+l;
  // myth[r] is this lane's own-query ((ln>>4)*4+r) threshold (group-uniform).
  float thr_reg = 3.0e38f;
  float myth[4] = {3.0e38f, 3.0e38f, 3.0e38f, 3.0e38f};

  // stage query tile, pull A fragments (hi/lo) to registers
  ushort* buf0 = cb;
  stage_c<F>(Xh, q0, buf0);
  stage_c<F>(Xl, q0, buf0 + 64 * F);
  __syncthreads();
  bf16x8 ah[KC], al[KC];
#pragma unroll
  for (int kc = 0; kc < KC; ++kc) {
    ah[kc] = ldfrag<F>(buf0, wv * 16, kc, ln);
    al[kc] = ldfrag<F>(buf0 + 64 * F, wv * 16, kc, ln);
  }
  __syncthreads();  // A-frag ds_reads drained before overwriting buf0
  stage_c<F>(Xh, cbase, buf0);
  stage_c<F>(Xl, cbase, buf0 + 64 * F);
  __syncthreads();  // tile 0 resident

  for (int t = 0; t < NT; ++t) {
    const int c0 = t * 64;
    float cn[4];
#pragma unroll
    for (int cg = 0; cg < 4; ++cg) cn[cg] = sqn[cbase + c0 + cg * 16 + (ln & 15)];

    // prefetch next tile into the other buffer (drained by end-of-loop barrier)
    if (t + 1 < NT) {
      ushort* nb = cb + (size_t)((t + 1) & 1) * (2 * 64 * F);
      stage_c<F>(Xh, cbase + (t + 1) * 64, nb);
      stage_c<F>(Xl, cbase + (t + 1) * 64, nb + 64 * F);
    }

    const ushort* hi = cb + (size_t)(t & 1) * (2 * 64 * F);
    const ushort* lo = hi + 64 * F;

    // MFMA: kc outer, cg inner -> 4 independent accumulator chains
    f32x4 acc[4];
#pragma unroll
    for (int cg = 0; cg < 4; ++cg) acc[cg] = (f32x4){0.f, 0.f, 0.f, 0.f};
#pragma unroll
    for (int kc = 0; kc < KC; ++kc) {
      bf16x8 bh[4], bl[4];
#pragma unroll
      for (int cg = 0; cg < 4; ++cg) {
        bh[cg] = ldfrag<F>(hi, cg * 16, kc, ln);
        bl[cg] = ldfrag<F>(lo, cg * 16, kc, ln);
      }
#pragma unroll
      for (int cg = 0; cg < 4; ++cg) {
        acc[cg] = __builtin_amdgcn_mfma_f32_16x16x32_bf16(ah[kc], bh[cg], acc[cg], 0, 0, 0);
        acc[cg] = __builtin_amdgcn_mfma_f32_16x16x32_bf16(al[kc], bh[cg], acc[cg], 0, 0, 0);
        acc[cg] = __builtin_amdgcn_mfma_f32_16x16x32_bf16(ah[kc], bl[cg], acc[cg], 0, 0, 0);
      }
    }

    // register-ballot selection: lane's score for (query (ln>>4)*4+r, cand cg*16+(ln&15))
#pragma unroll
    for (int cg = 0; cg < 4; ++cg) {
#pragma unroll
      for (int r = 0; r < 4; ++r) {
        float s = fmaf(-2.f, acc[cg][r], cn[cg]);
        unsigned long long m = __ballot(s < myth[r]);
        while (m) {
          int L = __ffsll(m) - 1;
          m &= m - 1;
          int g = L >> 4;
          int qk = g * 4 + r;                       // wave-uniform scalar
          float sv = __shfl(s, L);
          float th = __shfl(thr_reg, qk);
          if (sv >= th) continue;                   // tightened since ballot
          int ci = cbase + c0 + cg * 16 + (L & 15);
          int row = (wv * 16 + qk) * LIST;
          float dcur = (ln < LIST) ? Ld[row + ln] : 3.0e38f;
          int   icur = (ln < LIST) ? (int)Li[row + ln] : 0;
          unsigned long long le = __ballot(dcur <= sv);
          int p = __popcll(le & 0xFFFFFFFFull);     // insertion position (<=31)
          float dprev = __shfl_up(dcur, 1);
          int   iprev = __shfl_up(icur, 1);
          float nd = (ln < p) ? dcur : ((ln == p) ? sv : dprev);
          int   ni = (ln < p) ? icur : ((ln == p) ? ci : iprev);
          if (ln < LIST) { Ld[row + ln] = nd; Li[row + ln] = (ushort)ni; }
          float tnew = __shfl(nd, LIST - 1);
          thr_reg = (ln == qk) ? tnew : thr_reg;
          myth[r] = ((ln >> 4) == g) ? tnew : myth[r];
        }
      }
    }
    __syncthreads();  // drains next-tile stage; protects c-buffers
  }

#pragma unroll 1
  for (int k = 0; k < 16; ++k) {
    int q = wv * 16 + k;
    if (ln < LIST)
      out_cand[(size_t)(q0 + q) * (2 * LIST) + hf * LIST + ln] = (int)Li[q * LIST + ln];
  }
}

// Exact fp32 re-rank of the 64 union candidates -> true fp32 top-20 set.
// One wave per query; lane l handles candidate l.
template<int F>
__global__ __launch_bounds__(256) void refine_kernel(const float* __restrict__ X,
                                                     const float* __restrict__ sqn,
                                                     const int* __restrict__ cand,
                                                     int* __restrict__ out_idx) {
  const int wv = threadIdx.x >> 6, ln = threadIdx.x & 63;
  const int q = blockIdx.x * 4 + wv;
  int ci = cand[(size_t)q * (2 * LIST) + ln];
  const float* qrow = X + (size_t)q * F;
  const float* crow = X + (size_t)ci * F;
  float dot = 0.f;
#pragma unroll
  for (int d = 0; d < F; d += 4) {
    float4 qv = *(const float4*)(qrow + d);
    float4 cv = *(const float4*)(crow + d);
    dot += qv.x * cv.x + qv.y * cv.y + qv.z * cv.z + qv.w * cv.w;
  }
  float s = sqn[ci] - 2.0f * dot;
  // rank by (score asc, index asc) among the 64 candidates (halves are disjoint)
  int rank = 0;
#pragma unroll 1
  for (int j = 0; j < 64; ++j) {
    float sj = __shfl(s, j);
    int   cj = __shfl(ci, j);
    rank += (sj < s) || (sj == s && cj < ci);
  }
  bool win = rank < KNN;
  unsigned long long wm = __ballot(win);
  int pos = __popcll(wm & ((1ull << ln) - 1));
  if (win) out_idx[(size_t)q * KNN + pos] = ci;
}

// x1 = relu(pos @ W1 + b1) + bf16 hi/lo split + squared row norms.
__global__ __launch_bounds__(256) void mlp1_kernel(const float* __restrict__ pos,
                                                   const float* __restrict__ W1,
                                                   const float* __restrict__ b1,
                                                   float* __restrict__ x1,
                                                   ushort* __restrict__ xh,
                                                   ushort* __restrict__ xl,
                                                   float* __restrict__ sqn) {
  int i = blockIdx.x * 4 + (threadIdx.x >> 6);
  int o = threadIdx.x & 63;
  float p0 = pos[i * 3], p1 = pos[i * 3 + 1], p2 = pos[i * 3 + 2];
  float v = p0 * W1[o] + p1 * W1[64 + o] + p2 * W1[128 + o] + b1[o];
  v = fmaxf(v, 0.f);
  x1[(size_t)i * 64 + o] = v;
  __hip_bfloat16 h = __float2bfloat16(v);
  float hv = __bfloat162float(h);
  __hip_bfloat16 l2 = __float2bfloat16(v - hv);
  xh[(size_t)i * 64 + o] = *(ushort*)&h;
  xl[(size_t)i * 64 + o] = *(ushort*)&l2;
  float ss = v * v;
#pragma unroll
  for (int d = 32; d; d >>= 1) ss += __shfl_xor(ss, d);
  if (o == 0) sqn[i] = ss;
}

// hi/lo bf16 split + squared norms for an existing fp32 feature array.
template<int F>
__global__ __launch_bounds__(256) void prep_kernel(const float* __restrict__ x,
                                                   ushort* __restrict__ xh,
                                                   ushort* __restrict__ xl,
                                                   float* __restrict__ sqn) {
  int i = blockIdx.x * 4 + (threadIdx.x >> 6);
  int l = threadIdx.x & 63;
  float ss = 0.f;
#pragma unroll
  for (int d = l; d < F; d += 64) {
    float v = x[(size_t)i * F + d];
    ss += v * v;
    __hip_bfloat16 h = __float2bfloat16(v);
    float hv = __bfloat162float(h);
    __hip_bfloat16 l2 = __float2bfloat16(v - hv);
    xh[(size_t)i * F + d] = *(ushort*)&h;
    xl[(size_t)i * F + d] = *(ushort*)&l2;
  }
#pragma unroll
  for (int d = 32; d; d >>= 1) ss += __shfl_xor(ss, d);
  if (l == 0) sqn[i] = ss;
}

// C[N x OUT] = X[N x K] @ W[K x OUT] (+ bias). Register-tiled 4 rows x float4.
template<int K, int OUT, bool BIAS>
__global__ __launch_bounds__(256) void lin_kernel(const float* __restrict__ X,
                                                  const float* __restrict__ W,
                                                  const float* __restrict__ bias,
                                                  float* __restrict__ C) {
  constexpr int XD = OUT / 4;
  constexpr int YD = 256 / XD;
  constexpr int R = YD * 4;
  __shared__ float xs[R * K];
  const int tid = threadIdx.x;
  const int tx = tid % XD, ty = tid / XD;
  const size_t r0 = (size_t)blockIdx.x * R;
  const float4* Xv = (const float4*)(X + r0 * K);
  float4* xsv = (float4*)xs;
#pragma unroll
  for (int i2 = tid; i2 < R * K / 4; i2 += 256) xsv[i2] = Xv[i2];
  __syncthreads();
  float4 acc[4];
#pragma unroll
  for (int i = 0; i < 4; i++) acc[i] = make_float4(0.f, 0.f, 0.f, 0.f);
  const float4* W4 = (const float4*)W;
#pragma unroll 8
  for (int k = 0; k < K; ++k) {
    float4 wv = W4[k * XD + tx];
#pragma unroll
    for (int i = 0; i < 4; i++) {
      float xv = xs[(ty * 4 + i) * K + k];
      acc[i].x += xv * wv.x; acc[i].y += xv * wv.y;
      acc[i].z += xv * wv.z; acc[i].w += xv * wv.w;
    }
  }
  float4 bv = make_float4(0.f, 0.f, 0.f, 0.f);
  if (BIAS) bv = ((const float4*)bias)[tx];
#pragma unroll
  for (int i = 0; i < 4; i++) {
    float4 o;
    o.x = acc[i].x + bv.x; o.y = acc[i].y + bv.y;
    o.z = acc[i].z + bv.z; o.w = acc[i].w + bv.w;
    ((float4*)(C + (r0 + ty * 4 + i) * OUT))[tx] = o;
  }
}

// out_i = relu(P_i + max_j Q[idx[i][j]])
template<int OUT>
__global__ void maxpool_kernel(const float* __restrict__ P, const float* __restrict__ Q,
                               const int* __restrict__ idx, float* __restrict__ xo) {
  __shared__ int nb[KNN];
  int i = blockIdx.x;
  if (threadIdx.x < KNN) nb[threadIdx.x] = idx[(size_t)i * KNN + threadIdx.x];
  __syncthreads();
  int o = threadIdx.x;
  float m = -3.0e38f;
#pragma unroll
  for (int j = 0; j < KNN; j++) m = fmaxf(m, Q[(size_t)nb[j] * OUT + o]);
  float p = P[(size_t)i * OUT + o];
  xo[(size_t)i * OUT + o] = fmaxf(p + m, 0.f);
}

// Wp[k][o] = We[k][o] - We[K+k][o]
__global__ void wsub_kernel(const float* __restrict__ We, float* __restrict__ Wp, int total) {
  int t = blockIdx.x * 256 + threadIdx.x;
  if (t < total) Wp[t] = We[t] - We[total + t];
}

extern "C" void kernel_launch(void* const* d_in, const int* in_sizes, int n_in,
                              void* d_out, int out_size, void* d_ws, size_t ws_size,
                              hipStream_t stream) {
  const float* pos = (const float*)d_in[0];
  const float* W1  = (const float*)d_in[1];
  const float* b1  = (const float*)d_in[2];
  const float* We1 = (const float*)d_in[3];
  const float* be1 = (const float*)d_in[4];
  const float* We2 = (const float*)d_in[5];
  const float* be2 = (const float*)d_in[6];
  const float* W2  = (const float*)d_in[7];
  const float* b2  = (const float*)d_in[8];
  float* out = (float*)d_out;

  const size_t N = N_PTS;
  float* ws  = (float*)d_ws;
  float* x1  = ws;               // N*64
  float* P1  = x1 + N * 64;      // N*128
  float* Q1  = P1 + N * 128;     // N*128
  float* x2  = Q1 + N * 128;     // N*128
  float* P2  = x2 + N * 128;     // N*256
  float* Q2  = P2 + N * 256;     // N*256
  float* x3  = Q2 + N * 256;     // N*256
  float* sqn = x3 + N * 256;     // N (x1 norms, then x2 norms)
  float* Wp1 = sqn + N;          // 64*128
  float* Wp2 = Wp1 + 64 * 128;   // 128*256
  int* idx1  = (int*)(Wp2 + 128 * 256);  // N*20
  int* idx2  = idx1 + N * KNN;           // N*20
  int* cand  = idx2 + N * KNN;           // N*64 (two half-lists, reused per layer)
  ushort* X1h = (ushort*)(cand + N * 2 * LIST); // N*64
  ushort* X1l = X1h + N * 64;               // N*64
  ushort* X2h = X1l + N * 64;               // N*128
  ushort* X2l = X2h + N * 128;              // N*128
  size_t need = (size_t)((char*)(X2l + N * 128) - (char*)d_ws);
  if (ws_size < need) return;  // insufficient scratch -> visible failure

  auto lds_bytes = [](int F) {
    return (size_t)(4 * 64 * F) * 2 + (size_t)(64 * LIST) * 4 + (size_t)(64 * LIST) * 2;
  };
  size_t lds64 = lds_bytes(64), lds128 = lds_bytes(128);
  hipFuncSetAttribute(reinterpret_cast<const void*>(&knn_kernel<64>),
                      hipFuncAttributeMaxDynamicSharedMemorySize, (int)lds64);
  hipFuncSetAttribute(reinterpret_cast<const void*>(&knn_kernel<128>),
                      hipFuncAttributeMaxDynamicSharedMemorySize, (int)lds128);

  wsub_kernel<<<(64 * 128 + 255) / 256, 256, 0, stream>>>(We1, Wp1, 64 * 128);
  wsub_kernel<<<(128 * 256 + 255) / 256, 256, 0, stream>>>(We2, Wp2, 128 * 256);

  mlp1_kernel<<<N / 4, 256, 0, stream>>>(pos, W1, b1, x1, X1h, X1l, sqn);
  knn_kernel<64><<<N / 32, 256, lds64, stream>>>(X1h, X1l, sqn, cand);   // 512 blocks
  refine_kernel<64><<<N / 4, 256, 0, stream>>>(x1, sqn, cand, idx1);
  lin_kernel<64, 128, true ><<<N / 32, 256, 0, stream>>>(x1, Wp1, be1, P1);
  lin_kernel<64, 128, false><<<N / 32, 256, 0, stream>>>(x1, We1 + 64 * 128, nullptr, Q1);
  maxpool_kernel<128><<<N, 128, 0, stream>>>(P1, Q1, idx1, x2);

  prep_kernel<128><<<N / 4, 256, 0, stream>>>(x2, X2h, X2l, sqn);
  knn_kernel<128><<<N / 32, 256, lds128, stream>>>(X2h, X2l, sqn, cand); // 512 blocks
  refine_kernel<128><<<N / 4, 256, 0, stream>>>(x2, sqn, cand, idx2);
  lin_kernel<128, 256, true ><<<N / 16, 256, 0, stream>>>(x2, Wp2, be2, P2);
  lin_kernel<128, 256, false><<<N / 16, 256, 0, stream>>>(x2, We2 + 128 * 256, nullptr, Q2);
  maxpool_kernel<256><<<N, 256, 0, stream>>>(P2, Q2, idx2, x3);

  lin_kernel<256, 128, true ><<<N / 32, 256, 0, stream>>>(x3, W2, b2, out);
}

// Round 5
// 2045.165 us; speedup vs baseline: 2.4065x; 1.3934x over previous
//
#include <hip/hip_runtime.h>
#include <hip/hip_bf16.h>

#define N_PTS 16384
#define KNN   20
#define LIST  32   // approx-stage list width per candidate-half (refine is exact)

typedef unsigned int u32;
typedef const __attribute__((address_space(1))) u32 glob_u32;
typedef __attribute__((address_space(3))) u32 lds_u32;

typedef __attribute__((ext_vector_type(8))) short bf16x8;
typedef __attribute__((ext_vector_type(4))) float f32x4;

__device__ __forceinline__ void g2lds16(const void* g, void* l) {
  // async global->LDS, 16B per lane; LDS dest = wave-uniform base + lane*16
  __builtin_amdgcn_global_load_lds((glob_u32*)g, (lds_u32*)l, 16, 0, 0);
}

// Stage ROWS x F bf16 from X[row0..) into LDS with chunk-XOR swizzle:
// LDS 16B-chunk position p of row r holds global chunk (p ^ (r & (NCH-1))).
template<int F, int ROWS>
__device__ __forceinline__ void stage_c(const ushort* __restrict__ X, int row0, ushort* dst) {
  constexpr int NCH = F / 8;            // 16B chunks per row
  constexpr int TOT = ROWS * NCH;       // >= 256 for all instantiations
  const int tid = threadIdx.x;
  const int wv = tid >> 6, ln = tid & 63;
#pragma unroll
  for (int base = 0; base < TOT; base += 256) {
    int g = base + wv * 64 + ln;
    int r = g / NCH;
    int p = g & (NCH - 1);
    int sc = p ^ (r & (NCH - 1));       // pre-swizzled global source chunk
    g2lds16(X + (size_t)(row0 + r) * F + sc * 8,
            dst + (size_t)(base + wv * 64) * 8);   // wave-uniform LDS base
  }
}

// Load one 16x32 bf16 MFMA fragment from a swizzled LDS tile.
// lane: row = rbase + (ln&15), k-chunk pc = kc*4 + (ln>>4), de-swizzled.
template<int F>
__device__ __forceinline__ bf16x8 ldfrag(const ushort* buf, int rbase, int kc, int ln) {
  constexpr int NCH = F / 8;
  int r  = rbase + (ln & 15);
  int pc = kc * 4 + (ln >> 4);
  int sp = pc ^ (r & (NCH - 1));
  return *(const bf16x8*)(buf + (size_t)r * F + sp * 8);
}

// Fused bf16x3-MFMA distance + buffered top-32 kNN over HALF the candidate range.
// Block: 256 thr = 4 waves; wave owns 16 queries; 32-cand tiles, double-buffered.
// Selection: parallel survivor appends into per-query LDS buffers + rare
// wave-collective bitonic-64 merges (FAISS-style), instead of serial inserts.
template<int F>
__global__ __launch_bounds__(256) void knn_kernel(const ushort* __restrict__ Xh,
                                                  const ushort* __restrict__ Xl,
                                                  const float* __restrict__ sqn,
                                                  int* __restrict__ out_cand) {
  constexpr int KC = F / 32;            // 32-k chunks per row
  constexpr int NC = N_PTS / 2;         // candidates per block (2-way split)
  constexpr int TS = 32;                // candidate tile size
  constexpr int NT = NC / TS;
  extern __shared__ ushort lds_raw[];
  ushort* cb  = lds_raw;                          // [2 buf][2 part][TS*F]
  float*  Bs  = (float*)(cb + 4 * TS * F);        // 64*32 survivor scores
  ushort* Bi  = (ushort*)(Bs + 64 * LIST);        // 64*32 survivor indices
  float*  Ld  = (float*)(Bi + 64 * LIST);         // 64*32 sorted distances
  ushort* Li  = (ushort*)(Ld + 64 * LIST);        // 64*32 sorted indices

  const int tid = threadIdx.x;
  const int wv = tid >> 6, ln = tid & 63;
  const int q0 = (blockIdx.x >> 1) * 64;
  const int hf = blockIdx.x & 1;
  const int cbase = hf * NC;

  // init per-query sorted lists (wave-local rows)
#pragma unroll
  for (int k = 0; k < 16; ++k) {
    int row = (wv * 16 + k) * LIST;
    if (ln < LIST) { Ld[row + ln] = 3.0e38f; Li[row + ln] = 0; }
  }
  float thr_reg = 3.0e38f;   // lane l<16: 32nd-best for query wv*16+l
  float myth[4];             // this lane's own-query thresholds, myth[r] for q=(ln>>4)*4+r
#pragma unroll
  for (int r = 0; r < 4; ++r) myth[r] = 3.0e38f;
  int bcnt = 0;              // lane l<16: buffered-survivor count of query wv*16+l

  // wave-collective merge of query qk's buffer into its sorted top-32
  auto merge_q = [&](int qk) {
    int cnt = __shfl(bcnt, qk);
    int lrow = (wv * 16 + qk) * LIST;
    float key; int id;
    if (ln < 32) { key = Ld[lrow + ln]; id = (int)Li[lrow + ln]; }
    else {
      int j = ln - 32;
      bool v = j < cnt;
      key = v ? Bs[lrow + j] : 3.0e38f;
      id  = v ? (int)Bi[lrow + j] : 65535;
    }
    // bitonic sort 64 ascending by (key, id)
#pragma unroll
    for (int kk = 2; kk <= 64; kk <<= 1) {
#pragma unroll
      for (int jj = kk >> 1; jj > 0; jj >>= 1) {
        float ok = __shfl_xor(key, jj);
        int   oi = __shfl_xor(id, jj);
        bool pless = (ok < key) || (ok == key && oi < id);
        bool take = pless == (((ln & jj) == 0) == ((ln & kk) == 0));
        key = take ? ok : key;
        id  = take ? oi : id;
      }
    }
    if (ln < 32) { Ld[lrow + ln] = key; Li[lrow + ln] = (ushort)id; }
    float tnew = __shfl(key, 31);
    thr_reg = (ln == qk) ? tnew : thr_reg;
    bcnt    = (ln == qk) ? 0 : bcnt;
  };

  // stage query tile (64 rows, hi then lo across both buffers), pull A frags
  stage_c<F, 64>(Xh, q0, cb);
  stage_c<F, 64>(Xl, q0, cb + 64 * F);
  __syncthreads();
  bf16x8 ah[KC], al[KC];
#pragma unroll
  for (int kc = 0; kc < KC; ++kc) {
    ah[kc] = ldfrag<F>(cb, wv * 16, kc, ln);
    al[kc] = ldfrag<F>(cb + 64 * F, wv * 16, kc, ln);
  }
  __syncthreads();  // A-frag ds_reads drained before overwriting
  stage_c<F, TS>(Xh, cbase, cb);
  stage_c<F, TS>(Xl, cbase, cb + TS * F);
  __syncthreads();  // tile 0 resident

  for (int t = 0; t < NT; ++t) {
    const int c0 = t * TS;
    float cn[2];
#pragma unroll
    for (int cg = 0; cg < 2; ++cg) cn[cg] = sqn[cbase + c0 + cg * 16 + (ln & 15)];

    // prefetch next tile (drained by end-of-loop barrier)
    if (t + 1 < NT) {
      ushort* nb = cb + (size_t)((t + 1) & 1) * (2 * TS * F);
      stage_c<F, TS>(Xh, cbase + (t + 1) * TS, nb);
      stage_c<F, TS>(Xl, cbase + (t + 1) * TS, nb + TS * F);
    }

    const ushort* hi = cb + (size_t)(t & 1) * (2 * TS * F);
    const ushort* lo = hi + TS * F;

    // bf16x3 MFMA: split hi*hi and cross terms into independent chains
    f32x4 aH[2], aX[2];
#pragma unroll
    for (int cg = 0; cg < 2; ++cg) { aH[cg] = (f32x4){0,0,0,0}; aX[cg] = (f32x4){0,0,0,0}; }
#pragma unroll
    for (int kc = 0; kc < KC; ++kc) {
      bf16x8 bh0 = ldfrag<F>(hi, 0,  kc, ln);
      bf16x8 bh1 = ldfrag<F>(hi, 16, kc, ln);
      bf16x8 bl0 = ldfrag<F>(lo, 0,  kc, ln);
      bf16x8 bl1 = ldfrag<F>(lo, 16, kc, ln);
      aH[0] = __builtin_amdgcn_mfma_f32_16x16x32_bf16(ah[kc], bh0, aH[0], 0, 0, 0);
      aH[1] = __builtin_amdgcn_mfma_f32_16x16x32_bf16(ah[kc], bh1, aH[1], 0, 0, 0);
      aX[0] = __builtin_amdgcn_mfma_f32_16x16x32_bf16(al[kc], bh0, aX[0], 0, 0, 0);
      aX[1] = __builtin_amdgcn_mfma_f32_16x16x32_bf16(al[kc], bh1, aX[1], 0, 0, 0);
      aX[0] = __builtin_amdgcn_mfma_f32_16x16x32_bf16(ah[kc], bl0, aX[0], 0, 0, 0);
      aX[1] = __builtin_amdgcn_mfma_f32_16x16x32_bf16(ah[kc], bl1, aX[1], 0, 0, 0);
    }

    // selection: parallel appends per (cg, r) ballot group
#pragma unroll
    for (int cg = 0; cg < 2; ++cg) {
#pragma unroll
      for (int r = 0; r < 4; ++r) {
        // lane scores query (ln>>4)*4+r vs candidate c0+cg*16+(ln&15)
        float s = cn[cg] - 2.0f * (aH[cg][r] + aX[cg][r]);
        unsigned long long m = __ballot(s < myth[r]);
        if (m) {
          int qk = ((ln & 48) >> 2) + r;            // (ln>>4)*4 + r
          int basec = __shfl(bcnt, qk);             // uniform control here
          if (s < myth[r]) {
            int pos = basec +
                __popcll(m & (0xFFFFull << (ln & 48)) & ((1ull << ln) - 1));
            int brow = (wv * 16 + qk) * LIST;
            Bs[brow + pos] = s;
            Bi[brow + pos] = (ushort)(cbase + c0 + cg * 16 + (ln & 15));
          }
          if (ln < 16 && (ln & 3) == r)
            bcnt += __popcll((m >> ((ln >> 2) * 16)) & 0xFFFFull);
        }
      }
      // overflow merges: post-cg counts <= 32 (=cap); fold any > 16
      unsigned long long mm = __ballot(ln < 16 && bcnt > 16);
      if (mm) {
        do {
          int qk = __ffsll(mm) - 1;
          mm &= mm - 1;
          merge_q(qk);
        } while (mm);
#pragma unroll
        for (int rr = 0; rr < 4; ++rr) myth[rr] = __shfl(thr_reg, ((ln & 48) >> 2) + rr);
      }
    }
    __syncthreads();  // drains next-tile stage; protects c-buffers
  }

  // final flush of remaining buffered survivors
  {
    unsigned long long mm = __ballot(ln < 16 && bcnt > 0);
    while (mm) {
      int qk = __ffsll(mm) - 1;
      mm &= mm - 1;
      merge_q(qk);
    }
  }

#pragma unroll 1
  for (int k = 0; k < 16; ++k) {
    int q = wv * 16 + k;
    if (ln < LIST)
      out_cand[(size_t)(q0 + q) * (2 * LIST) + hf * LIST + ln] = (int)Li[q * LIST + ln];
  }
}

// Exact fp32 re-rank of the 64 union candidates -> true fp32 top-20 set.
// One wave per query; lane l handles candidate l.
template<int F>
__global__ __launch_bounds__(256) void refine_kernel(const float* __restrict__ X,
                                                     const float* __restrict__ sqn,
                                                     const int* __restrict__ cand,
                                                     int* __restrict__ out_idx) {
  const int wv = threadIdx.x >> 6, ln = threadIdx.x & 63;
  const int q = blockIdx.x * 4 + wv;
  int ci = cand[(size_t)q * (2 * LIST) + ln];
  const float* qrow = X + (size_t)q * F;
  const float* crow = X + (size_t)ci * F;
  float dot = 0.f;
#pragma unroll
  for (int d = 0; d < F; d += 4) {
    float4 qv = *(const float4*)(qrow + d);
    float4 cv = *(const float4*)(crow + d);
    dot += qv.x * cv.x + qv.y * cv.y + qv.z * cv.z + qv.w * cv.w;
  }
  float s = sqn[ci] - 2.0f * dot;
  // rank by (score asc, index asc) among the 64 candidates (halves are disjoint)
  int rank = 0;
#pragma unroll 1
  for (int j = 0; j < 64; ++j) {
    float sj = __shfl(s, j);
    int   cj = __shfl(ci, j);
    rank += (sj < s) || (sj == s && cj < ci);
  }
  bool win = rank < KNN;
  unsigned long long wm = __ballot(win);
  int pos = __popcll(wm & ((1ull << ln) - 1));
  if (win) out_idx[(size_t)q * KNN + pos] = ci;
}

// x1 = relu(pos @ W1 + b1) + bf16 hi/lo split + squared row norms.
__global__ __launch_bounds__(256) void mlp1_kernel(const float* __restrict__ pos,
                                                   const float* __restrict__ W1,
                                                   const float* __restrict__ b1,
                                                   float* __restrict__ x1,
                                                   ushort* __restrict__ xh,
                                                   ushort* __restrict__ xl,
                                                   float* __restrict__ sqn) {
  int i = blockIdx.x * 4 + (threadIdx.x >> 6);
  int o = threadIdx.x & 63;
  float p0 = pos[i * 3], p1 = pos[i * 3 + 1], p2 = pos[i * 3 + 2];
  float v = p0 * W1[o] + p1 * W1[64 + o] + p2 * W1[128 + o] + b1[o];
  v = fmaxf(v, 0.f);
  x1[(size_t)i * 64 + o] = v;
  __hip_bfloat16 h = __float2bfloat16(v);
  float hv = __bfloat162float(h);
  __hip_bfloat16 l2 = __float2bfloat16(v - hv);
  xh[(size_t)i * 64 + o] = *(ushort*)&h;
  xl[(size_t)i * 64 + o] = *(ushort*)&l2;
  float ss = v * v;
#pragma unroll
  for (int d = 32; d; d >>= 1) ss += __shfl_xor(ss, d);
  if (o == 0) sqn[i] = ss;
}

// hi/lo bf16 split + squared norms for an existing fp32 feature array.
template<int F>
__global__ __launch_bounds__(256) void prep_kernel(const float* __restrict__ x,
                                                   ushort* __restrict__ xh,
                                                   ushort* __restrict__ xl,
                                                   float* __restrict__ sqn) {
  int i = blockIdx.x * 4 + (threadIdx.x >> 6);
  int l = threadIdx.x & 63;
  float ss = 0.f;
#pragma unroll
  for (int d = l; d < F; d += 64) {
    float v = x[(size_t)i * F + d];
    ss += v * v;
    __hip_bfloat16 h = __float2bfloat16(v);
    float hv = __bfloat162float(h);
    __hip_bfloat16 l2 = __float2bfloat16(v - hv);
    xh[(size_t)i * F + d] = *(ushort*)&h;
    xl[(size_t)i * F + d] = *(ushort*)&l2;
  }
#pragma unroll
  for (int d = 32; d; d >>= 1) ss += __shfl_xor(ss, d);
  if (l == 0) sqn[i] = ss;
}

// C[N x OUT] = X[N x K] @ W[K x OUT] (+ bias). Register-tiled 4 rows x float4.
template<int K, int OUT, bool BIAS>
__global__ __launch_bounds__(256) void lin_kernel(const float* __restrict__ X,
                                                  const float* __restrict__ W,
                                                  const float* __restrict__ bias,
                                                  float* __restrict__ C) {
  constexpr int XD = OUT / 4;
  constexpr int YD = 256 / XD;
  constexpr int R = YD * 4;
  __shared__ float xs[R * K];
  const int tid = threadIdx.x;
  const int tx = tid % XD, ty = tid / XD;
  const size_t r0 = (size_t)blockIdx.x * R;
  const float4* Xv = (const float4*)(X + r0 * K);
  float4* xsv = (float4*)xs;
#pragma unroll
  for (int i2 = tid; i2 < R * K / 4; i2 += 256) xsv[i2] = Xv[i2];
  __syncthreads();
  float4 acc[4];
#pragma unroll
  for (int i = 0; i < 4; i++) acc[i] = make_float4(0.f, 0.f, 0.f, 0.f);
  const float4* W4 = (const float4*)W;
#pragma unroll 8
  for (int k = 0; k < K; ++k) {
    float4 wv = W4[k * XD + tx];
#pragma unroll
    for (int i = 0; i < 4; i++) {
      float xv = xs[(ty * 4 + i) * K + k];
      acc[i].x += xv * wv.x; acc[i].y += xv * wv.y;
      acc[i].z += xv * wv.z; acc[i].w += xv * wv.w;
    }
  }
  float4 bv = make_float4(0.f, 0.f, 0.f, 0.f);
  if (BIAS) bv = ((const float4*)bias)[tx];
#pragma unroll
  for (int i = 0; i < 4; i++) {
    float4 o;
    o.x = acc[i].x + bv.x; o.y = acc[i].y + bv.y;
    o.z = acc[i].z + bv.z; o.w = acc[i].w + bv.w;
    ((float4*)(C + (r0 + ty * 4 + i) * OUT))[tx] = o;
  }
}

// out_i = relu(P_i + max_j Q[idx[i][j]])
template<int OUT>
__global__ void maxpool_kernel(const float* __restrict__ P, const float* __restrict__ Q,
                               const int* __restrict__ idx, float* __restrict__ xo) {
  __shared__ int nb[KNN];
  int i = blockIdx.x;
  if (threadIdx.x < KNN) nb[threadIdx.x] = idx[(size_t)i * KNN + threadIdx.x];
  __syncthreads();
  int o = threadIdx.x;
  float m = -3.0e38f;
#pragma unroll
  for (int j = 0; j < KNN; j++) m = fmaxf(m, Q[(size_t)nb[j] * OUT + o]);
  float p = P[(size_t)i * OUT + o];
  xo[(size_t)i * OUT + o] = fmaxf(p + m, 0.f);
}

// Wp[k][o] = We[k][o] - We[K+k][o]
__global__ void wsub_kernel(const float* __restrict__ We, float* __restrict__ Wp, int total) {
  int t = blockIdx.x * 256 + threadIdx.x;
  if (t < total) Wp[t] = We[t] - We[total + t];
}

extern "C" void kernel_launch(void* const* d_in, const int* in_sizes, int n_in,
                              void* d_out, int out_size, void* d_ws, size_t ws_size,
                              hipStream_t stream) {
  const float* pos = (const float*)d_in[0];
  const float* W1  = (const float*)d_in[1];
  const float* b1  = (const float*)d_in[2];
  const float* We1 = (const float*)d_in[3];
  const float* be1 = (const float*)d_in[4];
  const float* We2 = (const float*)d_in[5];
  const float* be2 = (const float*)d_in[6];
  const float* W2  = (const float*)d_in[7];
  const float* b2  = (const float*)d_in[8];
  float* out = (float*)d_out;

  const size_t N = N_PTS;
  float* ws  = (float*)d_ws;
  float* x1  = ws;               // N*64
  float* P1  = x1 + N * 64;      // N*128
  float* Q1  = P1 + N * 128;     // N*128
  float* x2  = Q1 + N * 128;     // N*128
  float* P2  = x2 + N * 128;     // N*256
  float* Q2  = P2 + N * 256;     // N*256
  float* x3  = Q2 + N * 256;     // N*256
  float* sqn = x3 + N * 256;     // N (x1 norms, then x2 norms)
  float* Wp1 = sqn + N;          // 64*128
  float* Wp2 = Wp1 + 64 * 128;   // 128*256
  int* idx1  = (int*)(Wp2 + 128 * 256);  // N*20
  int* idx2  = idx1 + N * KNN;           // N*20
  int* cand  = idx2 + N * KNN;           // N*64 (two half-lists, reused per layer)
  ushort* X1h = (ushort*)(cand + N * 2 * LIST); // N*64
  ushort* X1l = X1h + N * 64;               // N*64
  ushort* X2h = X1l + N * 64;               // N*128
  ushort* X2l = X2h + N * 128;              // N*128
  size_t need = (size_t)((char*)(X2l + N * 128) - (char*)d_ws);
  if (ws_size < need) return;  // insufficient scratch -> visible failure

  auto lds_bytes = [](int F) {
    // cand dbuf (2 buf x 2 part x 32 rows) + Bs + Bi + Ld + Li
    return (size_t)(4 * 32 * F) * 2 +
           (size_t)(64 * LIST) * 4 + (size_t)(64 * LIST) * 2 +
           (size_t)(64 * LIST) * 4 + (size_t)(64 * LIST) * 2;
  };
  size_t lds64 = lds_bytes(64), lds128 = lds_bytes(128);
  hipFuncSetAttribute(reinterpret_cast<const void*>(&knn_kernel<64>),
                      hipFuncAttributeMaxDynamicSharedMemorySize, (int)lds64);
  hipFuncSetAttribute(reinterpret_cast<const void*>(&knn_kernel<128>),
                      hipFuncAttributeMaxDynamicSharedMemorySize, (int)lds128);

  wsub_kernel<<<(64 * 128 + 255) / 256, 256, 0, stream>>>(We1, Wp1, 64 * 128);
  wsub_kernel<<<(128 * 256 + 255) / 256, 256, 0, stream>>>(We2, Wp2, 128 * 256);

  mlp1_kernel<<<N / 4, 256, 0, stream>>>(pos, W1, b1, x1, X1h, X1l, sqn);
  knn_kernel<64><<<N / 32, 256, lds64, stream>>>(X1h, X1l, sqn, cand);   // 512 blocks
  refine_kernel<64><<<N / 4, 256, 0, stream>>>(x1, sqn, cand, idx1);
  lin_kernel<64, 128, true ><<<N / 32, 256, 0, stream>>>(x1, Wp1, be1, P1);
  lin_kernel<64, 128, false><<<N / 32, 256, 0, stream>>>(x1, We1 + 64 * 128, nullptr, Q1);
  maxpool_kernel<128><<<N, 128, 0, stream>>>(P1, Q1, idx1, x2);

  prep_kernel<128><<<N / 4, 256, 0, stream>>>(x2, X2h, X2l, sqn);
  knn_kernel<128><<<N / 32, 256, lds128, stream>>>(X2h, X2l, sqn, cand); // 512 blocks
  refine_kernel<128><<<N / 4, 256, 0, stream>>>(x2, sqn, cand, idx2);
  lin_kernel<128, 256, true ><<<N / 16, 256, 0, stream>>>(x2, Wp2, be2, P2);
  lin_kernel<128, 256, false><<<N / 16, 256, 0, stream>>>(x2, We2 + 128 * 256, nullptr, Q2);
  maxpool_kernel<256><<<N, 256, 0, stream>>>(P2, Q2, idx2, x3);

  lin_kernel<256, 128, true ><<<N / 32, 256, 0, stream>>>(x3, W2, b2, out);
}